// Round 2
// baseline (705.077 us; speedup 1.0000x reference)
//
#include <hip/hip_runtime.h>
#include <hip/hip_bf16.h>

#define N_NODES 100000
#define N_EDGES 1200000
#define G_GRAPHS 128
#define CAP 64      // max in-degree capacity (Poisson mean 12; P(overflow) ~ 1e-10)
#define WP 68       // padded LDS row stride (floats) to break transpose-store bank conflicts

// ---------------- CSR build (by dst) ----------------
__global__ void scatter_k(const int* __restrict__ ei, int* __restrict__ cnt,
                          int* __restrict__ adj) {
    int e = blockIdx.x * 256 + threadIdx.x;
    if (e >= N_EDGES) return;
    int s = ei[e];             // src
    int d = ei[N_EDGES + e];   // dst
    // defensive clamp: an out-of-range index would OOB-fault the dispatch
    s = min(max(s, 0), N_NODES - 1);
    d = min(max(d, 0), N_NODES - 1);
    int pos = atomicAdd(&cnt[d], 1);
    if (pos < CAP) adj[d * CAP + pos] = s;
}

// ---------------- embedding gather ----------------
__global__ void embed_k(const int* __restrict__ x, const float4* __restrict__ emb,
                        float4* __restrict__ h) {
    int t = blockIdx.x * 256 + threadIdx.x;
    if (t >= N_NODES * 16) return;
    int n = t >> 4, q = t & 15;
    h[n * 16 + q] = emb[x[n] * 16 + q];
}

// ---------------- neighbor aggregation (gather, no atomics) ----------------
__global__ void agg_k(const float4* __restrict__ h, const int* __restrict__ adj,
                      const int* __restrict__ cnt, float4* __restrict__ agg) {
    int t = blockIdx.x * 256 + threadIdx.x;
    int n = t >> 4, q = t & 15;     // 16 lanes per node, float4 per lane
    if (n >= N_NODES) return;
    int deg = cnt[n]; if (deg > CAP) deg = CAP;
    const int* al = adj + n * CAP;
    float4 acc = make_float4(0.f, 0.f, 0.f, 0.f);
    for (int i = 0; i < deg; ++i) {
        int s = al[i];
        float4 v = h[s * 16 + q];
        acc.x += v.x; acc.y += v.y; acc.z += v.z; acc.w += v.w;
    }
    agg[n * 16 + q] = acc;
}

// fully-unrolled 64x64 matvec: tout = (tin @ Wt^T) + bb, optional elu.
// wt is LDS, transposed layout wt[j*WP + k] = W[k][j] (row j contiguous in k).
__device__ __forceinline__ void matvec64(const float* wt, const float* bb,
                                         const float* tin, float* tout, bool do_elu) {
    #pragma unroll
    for (int j = 0; j < 64; ++j) {
        const float4* w = (const float4*)(wt + j * WP);
        float a0 = 0.f, a1 = 0.f, a2 = 0.f, a3 = 0.f;
        #pragma unroll
        for (int kq = 0; kq < 16; ++kq) {
            float4 wv = w[kq];   // broadcast LDS read (uniform address)
            a0 += tin[4 * kq + 0] * wv.x;
            a1 += tin[4 * kq + 1] * wv.y;
            a2 += tin[4 * kq + 2] * wv.z;
            a3 += tin[4 * kq + 3] * wv.w;
        }
        float acc = bb[j] + ((a0 + a1) + (a2 + a3));
        tout[j] = do_elu ? (acc > 0.f ? acc : expm1f(acc)) : acc;
    }
}

// ---------------- fused MLP+BN+elu (per layer), in-place on h ----------------
__global__ void __launch_bounds__(128) mlp_k(float* __restrict__ h,
    const float* __restrict__ agg,
    const float* __restrict__ W1, const float* __restrict__ b1,
    const float* __restrict__ g,  const float* __restrict__ be,
    const float* __restrict__ W2, const float* __restrict__ b2) {
    __shared__ float w1t[64 * WP];
    __shared__ float w2t[64 * WP];
    __shared__ float bb1[64];
    __shared__ float bb2[64];
    int tid = threadIdx.x;
    const float inv = rsqrtf(1.0f + 1e-5f);
    // transpose + fold BN scale into W1 columns
    for (int idx = tid; idx < 4096; idx += 128) {
        int k = idx >> 6, j = idx & 63;
        float s = g[j] * inv;
        w1t[j * WP + k] = W1[idx] * s;
        w2t[j * WP + k] = W2[idx];
    }
    if (tid < 64) {
        bb1[tid] = b1[tid] * (g[tid] * inv) + be[tid];
        bb2[tid] = b2[tid];
    }
    __syncthreads();
    int n = blockIdx.x * 128 + tid;
    if (n >= N_NODES) return;
    float t[64];
    const float4* hp = (const float4*)(h + n * 64);
    const float4* ap = (const float4*)(agg + n * 64);
    #pragma unroll
    for (int q = 0; q < 16; ++q) {
        float4 a = hp[q], b = ap[q];
        t[4 * q + 0] = a.x + b.x; t[4 * q + 1] = a.y + b.y;
        t[4 * q + 2] = a.z + b.z; t[4 * q + 3] = a.w + b.w;
    }
    float y[64];
    matvec64(w1t, bb1, t, y, true);   // inner BN+elu folded
    matvec64(w2t, bb2, y, t, true);   // + outer elu, result back into t
    float4* op = (float4*)(h + n * 64);
    #pragma unroll
    for (int q = 0; q < 16; ++q)
        op[q] = make_float4(t[4 * q + 0], t[4 * q + 1], t[4 * q + 2], t[4 * q + 3]);
}

// ---------------- mean pool per graph (batch sorted -> binary search bounds) ----
__global__ void pool_k(const float4* __restrict__ h, const int* __restrict__ batch,
                       float4* __restrict__ pooled) {
    int gph = blockIdx.x;
    int tid = threadIdx.x;          // 256
    int lo = 0, hi = N_NODES;
    while (lo < hi) { int mid = (lo + hi) >> 1; if (batch[mid] < gph) lo = mid + 1; else hi = mid; }
    int start = lo;
    hi = N_NODES;
    while (lo < hi) { int mid = (lo + hi) >> 1; if (batch[mid] < gph + 1) lo = mid + 1; else hi = mid; }
    int end = lo;
    int q = tid & 15, r = tid >> 4;
    float4 acc = make_float4(0.f, 0.f, 0.f, 0.f);
    for (int n = start + r; n < end; n += 16) {
        float4 v = h[n * 16 + q];
        acc.x += v.x; acc.y += v.y; acc.z += v.z; acc.w += v.w;
    }
    __shared__ float4 red[256];
    red[tid] = acc;
    __syncthreads();
    for (int s = 8; s > 0; s >>= 1) {
        if (r < s) {
            float4 o = red[(r + s) * 16 + q];
            float4 m = red[r * 16 + q];
            m.x += o.x; m.y += o.y; m.z += o.z; m.w += o.w;
            red[r * 16 + q] = m;
        }
        __syncthreads();
    }
    if (r == 0) {
        float invc = 1.0f / fmaxf((float)(end - start), 1.0f);
        float4 m = red[q];
        m.x *= invc; m.y *= invc; m.z *= invc; m.w *= invc;
        pooled[gph * 16 + q] = m;
    }
}

// ---------------- readout head: 128 graphs, one lane each ----------------
__global__ void __launch_bounds__(128) head_k(const float* __restrict__ pooled,
    const float* __restrict__ Wr1, const float* __restrict__ br1,
    const float* __restrict__ Wr2, const float* __restrict__ br2,
    const float* __restrict__ Wo,  const float* __restrict__ bo,
    float* __restrict__ out) {
    __shared__ float w1t[64 * WP];
    __shared__ float w2t[64 * WP];
    __shared__ float b1s[64], b2s[64], wos[64];
    int tid = threadIdx.x;
    for (int idx = tid; idx < 4096; idx += 128) {
        int k = idx >> 6, j = idx & 63;
        w1t[j * WP + k] = Wr1[idx];
        w2t[j * WP + k] = Wr2[idx];
    }
    if (tid < 64) { b1s[tid] = br1[tid]; b2s[tid] = br2[tid]; wos[tid] = Wo[tid]; }
    __syncthreads();
    int gph = tid;  // 0..127
    float t[64], y[64];
    const float4* pp = (const float4*)(pooled + gph * 64);
    #pragma unroll
    for (int q = 0; q < 16; ++q) {
        float4 v = pp[q];
        t[4 * q + 0] = v.x; t[4 * q + 1] = v.y; t[4 * q + 2] = v.z; t[4 * q + 3] = v.w;
    }
    matvec64(w1t, b1s, t, y, true);   // elu
    matvec64(w2t, b2s, y, t, false);  // no elu
    float o = bo[0];
    #pragma unroll
    for (int r = 0; r < 64; ++r) o += t[r] * wos[r];
    out[gph] = o;
}

extern "C" void kernel_launch(void* const* d_in, const int* in_sizes, int n_in,
                              void* d_out, int out_size, void* d_ws, size_t ws_size,
                              hipStream_t stream) {
    const int*   x     = (const int*)d_in[0];
    const int*   ei    = (const int*)d_in[1];
    const int*   batch = (const int*)d_in[2];
    const float* emb   = (const float*)d_in[3];
    const float* P[24];
    for (int i = 0; i < 24; ++i) P[i] = (const float*)d_in[4 + i];
    // P: [0..5]=layer a {W1,b1,g,be,W2,b2}, [6..11]=b, [12..17]=c,
    //    [18]=Wr1 [19]=br1 [20]=Wr2 [21]=br2 [22]=Wo [23]=bo

    char* ws = (char*)d_ws;
    float* h      = (float*)(ws + 0);           // 25.6 MB
    float* agg    = (float*)(ws + 25600000);    // 25.6 MB
    int*   adj    = (int*)  (ws + 51200000);    // 25.6 MB (N*CAP)
    int*   cnt    = (int*)  (ws + 76800000);    // 0.4 MB
    float* pooled = (float*)(ws + 77200000);    // 32 KB

    hipMemsetAsync(cnt, 0, N_NODES * sizeof(int), stream);
    scatter_k<<<(N_EDGES + 255) / 256, 256, 0, stream>>>(ei, cnt, adj);
    embed_k<<<(N_NODES * 16 + 255) / 256, 256, 0, stream>>>(x, (const float4*)emb, (float4*)h);
    for (int L = 0; L < 3; ++L) {
        const float* const* p = P + 6 * L;
        agg_k<<<(N_NODES * 16 + 255) / 256, 256, 0, stream>>>(
            (const float4*)h, adj, cnt, (float4*)agg);
        mlp_k<<<(N_NODES + 127) / 128, 128, 0, stream>>>(
            h, agg, p[0], p[1], p[2], p[3], p[4], p[5]);
    }
    pool_k<<<G_GRAPHS, 256, 0, stream>>>((const float4*)h, batch, (float4*)pooled);
    head_k<<<1, 128, 0, stream>>>(pooled, P[18], P[19], P[20], P[21], P[22], P[23],
                                  (float*)d_out);
}

// Round 4
// 678.162 us; speedup vs baseline: 1.0397x; 1.0397x over previous
//
#include <hip/hip_runtime.h>
#include <hip/hip_bf16.h>

#define N_NODES 100000
#define N_EDGES 1200000
#define G_GRAPHS 128
#define CAP 64      // max in-degree capacity (Poisson mean 12)
#define WP 68       // padded LDS row stride (floats) to break transpose-store bank conflicts

// ---------------- CSR build (by dst) ----------------
__global__ void scatter_k(const int* __restrict__ ei, int* __restrict__ cnt,
                          int* __restrict__ adj) {
    int e = blockIdx.x * 256 + threadIdx.x;
    if (e >= N_EDGES) return;
    int s = ei[e];             // src
    int d = ei[N_EDGES + e];   // dst
    s = min(max(s, 0), N_NODES - 1);
    d = min(max(d, 0), N_NODES - 1);
    int pos = atomicAdd(&cnt[d], 1);
    if (pos < CAP) adj[d * CAP + pos] = s;
}

// ---------------- embedding gather ----------------
__global__ void embed_k(const int* __restrict__ x, const float4* __restrict__ emb,
                        float4* __restrict__ h) {
    int t = blockIdx.x * 256 + threadIdx.x;
    if (t >= N_NODES * 16) return;
    int n = t >> 4, q = t & 15;
    h[n * 16 + q] = emb[x[n] * 16 + q];
}

__device__ __forceinline__ void f4add(float4& a, const float4 b) {
    a.x += b.x; a.y += b.y; a.z += b.z; a.w += b.w;
}

// ---------------- neighbor aggregation (gather, no atomics) ----------------
// 4-way unrolled with int4 adjacency loads: 4 outstanding gathers per lane.
__global__ void agg_k(const float4* __restrict__ h, const int* __restrict__ adj,
                      const int* __restrict__ cnt, float4* __restrict__ agg) {
    int t = blockIdx.x * 256 + threadIdx.x;
    int n = t >> 4, q = t & 15;     // 16 lanes per node, float4 per lane
    if (n >= N_NODES) return;
    int deg = cnt[n]; if (deg > CAP) deg = CAP;
    const int4* al4 = (const int4*)(adj + n * CAP);   // row base 256B-aligned
    float4 a0 = make_float4(0.f, 0.f, 0.f, 0.f);
    float4 a1 = a0, a2 = a0, a3 = a0;
    int d4 = deg >> 2;
    for (int i = 0; i < d4; ++i) {
        int4 s = al4[i];
        float4 v0 = h[s.x * 16 + q];
        float4 v1 = h[s.y * 16 + q];
        float4 v2 = h[s.z * 16 + q];
        float4 v3 = h[s.w * 16 + q];
        f4add(a0, v0); f4add(a1, v1); f4add(a2, v2); f4add(a3, v3);
    }
    const int* al = (const int*)al4;
    for (int i = d4 << 2; i < deg; ++i)
        f4add(a0, h[al[i] * 16 + q]);
    f4add(a0, a1); f4add(a2, a3); f4add(a0, a2);
    agg[n * 16 + q] = a0;
}

// fully-unrolled 64x64 matvec: tout = (tin @ Wt^T) + bb, optional elu.
// wt is LDS, transposed layout wt[j*WP + k] = W[k][j] (row j contiguous in k).
__device__ __forceinline__ void matvec64(const float* wt, const float* bb,
                                         const float* tin, float* tout, bool do_elu) {
    #pragma unroll
    for (int j = 0; j < 64; ++j) {
        const float4* w = (const float4*)(wt + j * WP);
        float a0 = 0.f, a1 = 0.f, a2 = 0.f, a3 = 0.f;
        #pragma unroll
        for (int kq = 0; kq < 16; ++kq) {
            float4 wv = w[kq];   // broadcast LDS read (uniform address)
            a0 += tin[4 * kq + 0] * wv.x;
            a1 += tin[4 * kq + 1] * wv.y;
            a2 += tin[4 * kq + 2] * wv.z;
            a3 += tin[4 * kq + 3] * wv.w;
        }
        float acc = bb[j] + ((a0 + a1) + (a2 + a3));
        tout[j] = do_elu ? (acc > 0.f ? acc : expm1f(acc)) : acc;
    }
}

// ---------------- fused MLP+BN+elu (per layer), in-place on h ----------------
// __launch_bounds__(128, 2): cap 256 VGPR so t[64]+y[64] stay in registers
// (default cap was 88 -> both arrays spilled to scratch; R2 showed 94us/layer).
__global__ void __launch_bounds__(128, 2) mlp_k(float* __restrict__ h,
    const float* __restrict__ agg,
    const float* __restrict__ W1, const float* __restrict__ b1,
    const float* __restrict__ g,  const float* __restrict__ be,
    const float* __restrict__ W2, const float* __restrict__ b2) {
    __shared__ float w1t[64 * WP];
    __shared__ float w2t[64 * WP];
    __shared__ float bb1[64];
    __shared__ float bb2[64];
    int tid = threadIdx.x;
    const float inv = rsqrtf(1.0f + 1e-5f);
    // transpose + fold BN scale into W1 columns
    for (int idx = tid; idx < 4096; idx += 128) {
        int k = idx >> 6, j = idx & 63;
        float s = g[j] * inv;
        w1t[j * WP + k] = W1[idx] * s;
        w2t[j * WP + k] = W2[idx];
    }
    if (tid < 64) {
        bb1[tid] = b1[tid] * (g[tid] * inv) + be[tid];
        bb2[tid] = b2[tid];
    }
    __syncthreads();
    int n = blockIdx.x * 128 + tid;
    if (n >= N_NODES) return;
    float t[64];
    const float4* hp = (const float4*)(h + n * 64);
    const float4* ap = (const float4*)(agg + n * 64);
    #pragma unroll
    for (int q = 0; q < 16; ++q) {
        float4 a = hp[q], b = ap[q];
        t[4 * q + 0] = a.x + b.x; t[4 * q + 1] = a.y + b.y;
        t[4 * q + 2] = a.z + b.z; t[4 * q + 3] = a.w + b.w;
    }
    float y[64];
    matvec64(w1t, bb1, t, y, true);   // inner BN+elu folded
    matvec64(w2t, bb2, y, t, true);   // + outer elu, result back into t
    float4* op = (float4*)(h + n * 64);
    #pragma unroll
    for (int q = 0; q < 16; ++q)
        op[q] = make_float4(t[4 * q + 0], t[4 * q + 1], t[4 * q + 2], t[4 * q + 3]);
}

// ---------------- mean pool per graph (batch sorted -> binary search bounds) ----
__global__ void pool_k(const float4* __restrict__ h, const int* __restrict__ batch,
                       float4* __restrict__ pooled) {
    int gph = blockIdx.x;
    int tid = threadIdx.x;          // 256
    int lo = 0, hi = N_NODES;
    while (lo < hi) { int mid = (lo + hi) >> 1; if (batch[mid] < gph) lo = mid + 1; else hi = mid; }
    int start = lo;
    hi = N_NODES;
    while (lo < hi) { int mid = (lo + hi) >> 1; if (batch[mid] < gph + 1) lo = mid + 1; else hi = mid; }
    int end = lo;
    int q = tid & 15, r = tid >> 4;
    float4 acc = make_float4(0.f, 0.f, 0.f, 0.f);
    for (int n = start + r; n < end; n += 16) {
        float4 v = h[n * 16 + q];
        acc.x += v.x; acc.y += v.y; acc.z += v.z; acc.w += v.w;
    }
    __shared__ float4 red[256];
    red[tid] = acc;
    __syncthreads();
    for (int s = 8; s > 0; s >>= 1) {
        if (r < s) {
            float4 o = red[(r + s) * 16 + q];
            float4 m = red[r * 16 + q];
            m.x += o.x; m.y += o.y; m.z += o.z; m.w += o.w;
            red[r * 16 + q] = m;
        }
        __syncthreads();
    }
    if (r == 0) {
        float invc = 1.0f / fmaxf((float)(end - start), 1.0f);
        float4 m = red[q];
        m.x *= invc; m.y *= invc; m.z *= invc; m.w *= invc;
        pooled[gph * 16 + q] = m;
    }
}

// ---------------- readout head: 128 graphs, one lane each ----------------
__global__ void __launch_bounds__(128, 2) head_k(const float* __restrict__ pooled,
    const float* __restrict__ Wr1, const float* __restrict__ br1,
    const float* __restrict__ Wr2, const float* __restrict__ br2,
    const float* __restrict__ Wo,  const float* __restrict__ bo,
    float* __restrict__ out) {
    __shared__ float w1t[64 * WP];
    __shared__ float w2t[64 * WP];
    __shared__ float b1s[64], b2s[64], wos[64];
    int tid = threadIdx.x;
    for (int idx = tid; idx < 4096; idx += 128) {
        int k = idx >> 6, j = idx & 63;
        w1t[j * WP + k] = Wr1[idx];
        w2t[j * WP + k] = Wr2[idx];
    }
    if (tid < 64) { b1s[tid] = br1[tid]; b2s[tid] = br2[tid]; wos[tid] = Wo[tid]; }
    __syncthreads();
    int gph = tid;  // 0..127
    float t[64], y[64];
    const float4* pp = (const float4*)(pooled + gph * 64);
    #pragma unroll
    for (int q = 0; q < 16; ++q) {
        float4 v = pp[q];
        t[4 * q + 0] = v.x; t[4 * q + 1] = v.y; t[4 * q + 2] = v.z; t[4 * q + 3] = v.w;
    }
    matvec64(w1t, b1s, t, y, true);   // elu
    matvec64(w2t, b2s, y, t, false);  // no elu
    float o = bo[0];
    #pragma unroll
    for (int r = 0; r < 64; ++r) o += t[r] * wos[r];
    out[gph] = o;
}

extern "C" void kernel_launch(void* const* d_in, const int* in_sizes, int n_in,
                              void* d_out, int out_size, void* d_ws, size_t ws_size,
                              hipStream_t stream) {
    const int*   x     = (const int*)d_in[0];
    const int*   ei    = (const int*)d_in[1];
    const int*   batch = (const int*)d_in[2];
    const float* emb   = (const float*)d_in[3];
    const float* P[24];
    for (int i = 0; i < 24; ++i) P[i] = (const float*)d_in[4 + i];

    char* ws = (char*)d_ws;
    float* h      = (float*)(ws + 0);           // 25.6 MB
    float* agg    = (float*)(ws + 25600000);    // 25.6 MB
    int*   adj    = (int*)  (ws + 51200000);    // 25.6 MB (N*CAP)
    int*   cnt    = (int*)  (ws + 76800000);    // 0.4 MB
    float* pooled = (float*)(ws + 77200000);    // 32 KB

    hipMemsetAsync(cnt, 0, N_NODES * sizeof(int), stream);
    scatter_k<<<(N_EDGES + 255) / 256, 256, 0, stream>>>(ei, cnt, adj);
    embed_k<<<(N_NODES * 16 + 255) / 256, 256, 0, stream>>>(x, (const float4*)emb, (float4*)h);
    for (int L = 0; L < 3; ++L) {
        const float* const* p = P + 6 * L;
        agg_k<<<(N_NODES * 16 + 255) / 256, 256, 0, stream>>>(
            (const float4*)h, adj, cnt, (float4*)agg);
        mlp_k<<<(N_NODES + 127) / 128, 128, 0, stream>>>(
            h, agg, p[0], p[1], p[2], p[3], p[4], p[5]);
    }
    pool_k<<<G_GRAPHS, 256, 0, stream>>>((const float4*)h, batch, (float4*)pooled);
    head_k<<<1, 128, 0, stream>>>(pooled, P[18], P[19], P[20], P[21], P[22], P[23],
                                  (float*)d_out);
}